// Round 3
// baseline (537.579 us; speedup 1.0000x reference)
//
#include <hip/hip_runtime.h>
#include <math.h>

#define HW (512 * 512)
#define NB 16
#define NTHR 256
#define BPB 64   // blocks per batch; iters = HW/(BPB*NTHR*4) = 4

// ---- workspace layout (4-byte words) ----
// zeroed region:
#define OFF_KCNT   0                      // f [16][8]
#define OFF_TCNT   (OFF_KCNT + 128)      // f [16][8]
#define OFF_KSUM   (OFF_TCNT + 128)      // f [16][32]
#define OFF_POS    (OFF_KSUM + 512)      // f [16]
#define OFF_AK     (OFF_POS + 16)
#define OFF_BK     (OFF_AK + 16)
#define OFF_CK     (OFF_BK + 16)
#define OFF_AT     (OFF_CK + 16)
#define OFF_BT     (OFF_AT + 16)
#define OFF_CT     (OFF_BT + 16)
#define OFF_AGGR   (OFF_CT + 16)         // f [16] (w-weighted lg sums)
#define OFF_NEGC   (OFF_AGGR + 16)       // u [16]
#define OFF_HISTFB (OFF_NEGC + 16)       // u [4][16][256] fallback hists
#define ZERO_WORDS (OFF_HISTFB + 4 * 16 * 256)
// non-zeroed region:
#define OFF_TBL    ZERO_WORDS            // f [16][9][5]: rows 0..8 = {a0..a3, w}
#define OFF_THR    (OFF_TBL + 16 * 45)   // f [16]
#define OFF_FB     (OFF_THR + 16)        // u [16]
#define OFF_NVAL   (OFF_FB + 16)         // u [16]
#define OFF_DISCR  (OFF_NVAL + 16)       // f [16]
#define OFF_PREFIX (OFF_DISCR + 16)      // u [16] (fallback select state)
#define OFF_KKC    (OFF_PREFIX + 16)     // u [16]
#define OFF_KEYS   (OFF_KKC + 16)        // u [16][HW] compacted neg keys
#define WS_FULL_BYTES ((size_t)(OFF_KEYS + NB * HW) * 4)

__device__ __forceinline__ unsigned fmap(float f) {
    unsigned u = __float_as_uint(f);
    return (u & 0x80000000u) ? ~u : (u | 0x80000000u);
}
__device__ __forceinline__ float funmap(unsigned u) {
    return (u & 0x80000000u) ? __uint_as_float(u & 0x7FFFFFFFu)
                             : __uint_as_float(~u);
}
__device__ __forceinline__ float wred(float x) {
#pragma unroll
    for (int o = 32; o; o >>= 1) x += __shfl_xor(x, o);
    return x;
}

// ---------------- K1: stats + kernel-dice + negative-key compaction ----------------
// __launch_bounds__(256,2): cap at 256 VGPR so the ~110 live regs do NOT spill
// to scratch (round-2 post-mortem: default budget forced VGPR=60 + scratch
// round-trips -> 210us latency-bound kernel).
__global__ __launch_bounds__(NTHR, 2) void k_stats(const float* __restrict__ preds,
                        const int* __restrict__ text,
                        const int* __restrict__ kern,
                        const int* __restrict__ mask,
                        unsigned* __restrict__ wsu, int do_compact) {
    float* wsf = (float*)wsu;
    const int b = blockIdx.y;
    const int tid = threadIdx.x;
    const int lane = tid & 63;
    const unsigned long long lmask = (1ull << lane) - 1ull;
    __shared__ float sacc[52];
    if (tid < 52) sacc[tid] = 0.f;
    __syncthreads();

    const int* tb = text + b * HW;
    const int* kb = kern + b * HW;
    const int* mb = mask + b * HW;
    const float* p0 = preds + (size_t)(b * 6 + 0) * HW;
    const float* p1 = preds + (size_t)(b * 6 + 1) * HW;
    const float* e0 = preds + (size_t)(b * 6 + 2) * HW;
    const float* e1 = e0 + HW;
    const float* e2 = e0 + 2 * HW;
    const float* e3 = e0 + 3 * HW;
    unsigned* keys = wsu + OFF_KEYS + (size_t)b * HW;

    // per-lane float accumulators (32 + 3); counts accumulate wave-uniform in SGPRs
    float ks[32];
#pragma unroll
    for (int i = 0; i < 32; i++) ks[i] = 0.f;
    float r_ak = 0.f, r_bk = 0.f, r_ck = 0.f;
    unsigned kcW[8] = {0, 0, 0, 0, 0, 0, 0, 0};
    unsigned tcW[8] = {0, 0, 0, 0, 0, 0, 0, 0};
    unsigned posW = 0;

    for (int base = (blockIdx.x * NTHR + tid) * 4; base < HW; base += BPB * NTHR * 4) {
        const int4 t4 = *(const int4*)(tb + base);
        const int4 k4 = *(const int4*)(kb + base);
        const int4 m4 = *(const int4*)(mb + base);
        const float4 s4 = *(const float4*)(p0 + base);
        const float4 q4 = *(const float4*)(p1 + base);
        const float4 a4 = *(const float4*)(e0 + base);
        const float4 b4 = *(const float4*)(e1 + base);
        const float4 c4 = *(const float4*)(e2 + base);
        const float4 d4 = *(const float4*)(e3 + base);

#define PIX(T, K, M, Q, A, B, C, D) do {                                     \
        bool pos_ = (T) > 0, mp_ = (M) > 0;                                  \
        float sm_ = (pos_ && mp_) ? 1.f : 0.f;                               \
        float sg_ = 1.f / (1.f + expf(-(Q)));                                \
        float ik_ = ((K) > 0) ? 1.f : 0.f;                                   \
        r_ak += sm_ * sg_ * ik_;                                             \
        r_bk += sm_ * sg_ * sg_;                                             \
        r_ck += sm_ * ik_;                                                   \
        posW += (unsigned)__popcll(__ballot(pos_ && mp_));                   \
        _Pragma("unroll")                                                    \
        for (int i_ = 0; i_ < 8; i_++) {                                     \
            bool hit_ = ((K) == i_ + 1);                                     \
            kcW[i_] += (unsigned)__popcll(__ballot(hit_));                   \
            tcW[i_] += (unsigned)__popcll(__ballot((T) == i_ + 1));          \
            float h_ = hit_ ? 1.f : 0.f;                                     \
            ks[i_ * 4 + 0] += h_ * (A);                                      \
            ks[i_ * 4 + 1] += h_ * (B);                                      \
            ks[i_ * 4 + 2] += h_ * (C);                                      \
            ks[i_ * 4 + 3] += h_ * (D);                                      \
        }                                                                    \
    } while (0)

        PIX(t4.x, k4.x, m4.x, q4.x, a4.x, b4.x, c4.x, d4.x);
        PIX(t4.y, k4.y, m4.y, q4.y, a4.y, b4.y, c4.y, d4.y);
        PIX(t4.z, k4.z, m4.z, q4.z, a4.z, b4.z, c4.z, d4.z);
        PIX(t4.w, k4.w, m4.w, q4.w, a4.w, b4.w, c4.w, d4.w);
#undef PIX

        // ---- negative-key compaction via ballot rank (no scan chain) ----
        unsigned long long m0 = __ballot(t4.x == 0);
        unsigned long long m1 = __ballot(t4.y == 0);
        unsigned long long m2 = __ballot(t4.z == 0);
        unsigned long long m3 = __ballot(t4.w == 0);
        unsigned c0 = (unsigned)__popcll(m0), c1 = (unsigned)__popcll(m1);
        unsigned c2 = (unsigned)__popcll(m2), c3 = (unsigned)__popcll(m3);
        unsigned tot = c0 + c1 + c2 + c3;
        unsigned bs = 0;
        if (lane == 0 && tot) bs = atomicAdd(&wsu[OFF_NEGC + b], tot);
        bs = __shfl(bs, 0);
        if (do_compact && tot) {
            if (t4.x == 0) keys[bs + (unsigned)__popcll(m0 & lmask)] = fmap(s4.x);
            if (t4.y == 0) keys[bs + c0 + (unsigned)__popcll(m1 & lmask)] = fmap(s4.y);
            if (t4.z == 0) keys[bs + c0 + c1 + (unsigned)__popcll(m2 & lmask)] = fmap(s4.z);
            if (t4.w == 0) keys[bs + c0 + c1 + c2 + (unsigned)__popcll(m3 & lmask)] = fmap(s4.w);
        }
    }

    // ---- epilogue: butterfly the 35 per-lane floats, scalars by lane 0 ----
#pragma unroll
    for (int i = 0; i < 32; i++) {
        float v = wred(ks[i]);
        if (lane == 0) atomicAdd(&sacc[16 + i], v);
    }
    {
        float v = wred(r_ak); if (lane == 0) atomicAdd(&sacc[49], v);
        v = wred(r_bk); if (lane == 0) atomicAdd(&sacc[50], v);
        v = wred(r_ck); if (lane == 0) atomicAdd(&sacc[51], v);
    }
    if (lane == 0) {
#pragma unroll
        for (int i = 0; i < 8; i++) {
            atomicAdd(&sacc[i], (float)kcW[i]);
            atomicAdd(&sacc[8 + i], (float)tcW[i]);
        }
        atomicAdd(&sacc[48], (float)posW);
    }
    __syncthreads();
    if (tid < 52) {
        float v = sacc[tid];
        int gi;
        if (tid < 8) gi = OFF_KCNT + b * 8 + tid;
        else if (tid < 16) gi = OFF_TCNT + b * 8 + (tid - 8);
        else if (tid < 48) gi = OFF_KSUM + b * 32 + (tid - 16);
        else if (tid == 48) gi = OFF_POS + b;
        else if (tid == 49) gi = OFF_AK + b;
        else if (tid == 50) gi = OFF_BK + b;
        else gi = OFF_CK + b;
        atomicAdd(&wsf[gi], v);
    }
}

// ---------------- K2: setup (avgs, w, discr, OHEM params) + 4-pass radix select ----------------
__global__ void k_sel(unsigned* __restrict__ wsu, int do_select) {
    float* wsf = (float*)wsu;
    const int b = blockIdx.x;
    const int tid = threadIdx.x;
    __shared__ float s_avg[8][4];
    __shared__ int s_valid[8];
    __shared__ unsigned s_hist[256];
    __shared__ unsigned s_kk, s_prefix;

    if (tid < 8) {
        float kcf = wsf[OFF_KCNT + b * 8 + tid];
        float tcf = wsf[OFF_TCNT + b * 8 + tid];
        int valid = (kcf > 0.f && tcf > 0.f) ? 1 : 0;
        float inv = 1.f / fmaxf(kcf, 1.f);
        float w = valid ? 1.f / fmaxf(tcf, 1.f) : 0.f;
#pragma unroll
        for (int c = 0; c < 4; c++) {
            float a = wsf[OFF_KSUM + b * 32 + tid * 4 + c] * inv;
            s_avg[tid][c] = a;
            wsf[OFF_TBL + b * 45 + (tid + 1) * 5 + c] = a;
        }
        s_valid[tid] = valid;
        wsf[OFF_TBL + b * 45 + (tid + 1) * 5 + 4] = w;
    }
    if (tid < 5) wsf[OFF_TBL + b * 45 + tid] = 0.f;  // background row
    __syncthreads();
    if (tid == 0) {
        int nval = 0;
        for (int i = 0; i < 8; i++) nval += s_valid[i];
        float L = 0.f;
        for (int i = 0; i < 8; i++)
            for (int j = i + 1; j < 8; j++)
                if (s_valid[i] && s_valid[j]) {
                    float sq = 0.f;
                    for (int c = 0; c < 4; c++) {
                        float d = s_avg[i][c] - s_avg[j][c];
                        sq += d * d;
                    }
                    float h = fmaxf(3.0f - sqrtf(sq), 0.f);
                    L += log1pf(h * h);
                }
        wsf[OFF_DISCR + b] = (nval > 1) ? L / fmaxf((float)(nval * (nval - 1)), 1.f) : 0.f;
        wsu[OFF_NVAL + b] = (unsigned)nval;
        unsigned pos = (unsigned)wsf[OFF_POS + b];
        unsigned neg = wsu[OFF_NEGC + b];
        unsigned nn = min(pos * 3u, neg);
        int fb = (pos == 0u || nn == 0u) ? 1 : 0;
        wsu[OFF_FB + b] = (unsigned)fb;
        s_kk = fb ? 0u : nn;
        s_prefix = 0u;
        wsu[OFF_KKC + b] = fb ? 0u : nn;   // fallback path state
        wsu[OFF_PREFIX + b] = 0u;
        wsf[OFF_THR + b] = 0.f;
    }
    __syncthreads();
    if (!do_select) return;
    if (s_kk == 0u) return;
    const unsigned count = wsu[OFF_NEGC + b];
    const unsigned* keys = wsu + OFF_KEYS + (size_t)b * HW;
    unsigned prefix = 0u, kk = s_kk;
    for (int pass = 0; pass < 4; pass++) {
        const int shift = 24 - 8 * pass;
        const unsigned fmask = (pass == 0) ? 0u : (0xFFFFFFFFu << (shift + 8));
        s_hist[tid] = 0u;
        __syncthreads();
        for (unsigned i = tid; i < count; i += NTHR) {
            unsigned key = keys[i];
            if ((key & fmask) == prefix) atomicAdd(&s_hist[(key >> shift) & 255u], 1u);
        }
        __syncthreads();
        if (tid == 0) {
            unsigned k2 = kk;
            for (int bin = 255; bin >= 0; --bin) {
                unsigned c = s_hist[bin];
                if (k2 <= c) { s_prefix = prefix | (((unsigned)bin) << shift); s_kk = k2; break; }
                k2 -= c;
            }
        }
        __syncthreads();
        prefix = s_prefix;
        kk = s_kk;
    }
    if (tid == 0) wsf[OFF_THR + b] = funmap(prefix);
}

// ---------------- fallback radix select over raw data (only if ws too small) ----------------
__global__ void k_hist(const float* __restrict__ preds, const int* __restrict__ text,
                       unsigned* __restrict__ wsu, int pass) {
    const int b = blockIdx.y;
    const int tid = threadIdx.x;
    __shared__ unsigned h[256];
    h[tid] = 0u;
    __syncthreads();
    const unsigned prefix = wsu[OFF_PREFIX + b];
    const int shift = 24 - 8 * pass;
    const unsigned fmask = (pass == 0) ? 0u : (0xFFFFFFFFu << (shift + 8));
    const int* tb = text + b * HW;
    const float* pt = preds + (size_t)(b * 6) * HW;
    for (int p = blockIdx.x * NTHR + tid; p < HW; p += gridDim.x * NTHR) {
        if (tb[p] == 0) {
            unsigned key = fmap(pt[p]);
            if ((key & fmask) == prefix) atomicAdd(&h[(key >> shift) & 255u], 1u);
        }
    }
    __syncthreads();
    if (h[tid]) atomicAdd(&wsu[OFF_HISTFB + pass * 4096 + b * 256 + tid], h[tid]);
}
__global__ void k_select(unsigned* __restrict__ wsu, int pass) {
    int b = threadIdx.x;
    if (b >= NB) return;
    float* wsf = (float*)wsu;
    unsigned k = wsu[OFF_KKC + b];
    unsigned prefix = wsu[OFF_PREFIX + b];
    const int shift = 24 - 8 * pass;
    const unsigned* h = &wsu[OFF_HISTFB + pass * 4096 + b * 256];
    if (k > 0) {
        for (int bin = 255; bin >= 0; --bin) {
            unsigned c = h[bin];
            if (k <= c) { prefix |= ((unsigned)bin) << shift; break; }
            k -= c;
        }
        wsu[OFF_KKC + b] = k;
        wsu[OFF_PREFIX + b] = prefix;
    }
    if (pass == 3) wsf[OFF_THR + b] = funmap(prefix);
}

// ---------------- K3: fused aggregation + OHEM text-dice pixel pass ----------------
__global__ __launch_bounds__(NTHR, 2) void k_pix(const float* __restrict__ preds,
                      const int* __restrict__ text,
                      const int* __restrict__ mask,
                      unsigned* __restrict__ wsu) {
    float* wsf = (float*)wsu;
    const int b = blockIdx.y;
    const int tid = threadIdx.x;
    const int lane = tid & 63;
    __shared__ float stbl[45];
    __shared__ float sred[4];
    __shared__ float sthr;
    __shared__ unsigned sfb;
    if (tid < 45) stbl[tid] = wsf[OFF_TBL + b * 45 + tid];
    if (tid < 4) sred[tid] = 0.f;
    if (tid == 0) { sthr = wsf[OFF_THR + b]; sfb = wsu[OFF_FB + b]; }
    __syncthreads();
    const float thr = sthr;
    const bool fb = sfb != 0u;
    float r_at = 0.f, r_bt = 0.f, r_ct = 0.f, r_ag = 0.f;
    const int* tb = text + b * HW;
    const int* mb = mask + b * HW;
    const float* p0 = preds + (size_t)(b * 6) * HW;
    const float* e0 = preds + (size_t)(b * 6 + 2) * HW;
    const float* e1 = e0 + HW;
    const float* e2 = e0 + 2 * HW;
    const float* e3 = e0 + 3 * HW;
    for (int base = (blockIdx.x * NTHR + tid) * 4; base < HW; base += BPB * NTHR * 4) {
        const int4 t4 = *(const int4*)(tb + base);
        const int4 m4 = *(const int4*)(mb + base);
        const float4 s4 = *(const float4*)(p0 + base);
        const float4 a4 = *(const float4*)(e0 + base);
        const float4 b4 = *(const float4*)(e1 + base);
        const float4 c4 = *(const float4*)(e2 + base);
        const float4 d4 = *(const float4*)(e3 + base);

#define PPIX(T, M, S, A, B, C, D) do {                                       \
        bool pos_ = (T) > 0;                                                 \
        bool samp_ = fb ? ((M) > 0) : ((((S) >= thr) || pos_) && ((M) > 0)); \
        float sg_ = 1.f / (1.f + expf(-(S)));                                \
        float smf_ = samp_ ? 1.f : 0.f;                                      \
        float it_ = pos_ ? 1.f : 0.f;                                        \
        r_at += smf_ * sg_ * it_;                                            \
        r_bt += smf_ * sg_ * sg_;                                            \
        r_ct += smf_ * it_;                                                  \
        int t5_ = min((T), 8) * 5;                                           \
        float d0_ = (A) - stbl[t5_ + 0];                                     \
        float d1_ = (B) - stbl[t5_ + 1];                                     \
        float d2_ = (C) - stbl[t5_ + 2];                                     \
        float d3_ = (D) - stbl[t5_ + 3];                                     \
        float w_ = stbl[t5_ + 4];                                            \
        float sq_ = d0_ * d0_ + d1_ * d1_ + d2_ * d2_ + d3_ * d3_;           \
        float dist_ = sqrtf(sq_ + 1e-12f) - 0.5f;                            \
        float hp_ = fmaxf(dist_, 0.f);                                       \
        r_ag += w_ * log1pf(hp_ * hp_);                                      \
    } while (0)

        PPIX(t4.x, m4.x, s4.x, a4.x, b4.x, c4.x, d4.x);
        PPIX(t4.y, m4.y, s4.y, a4.y, b4.y, c4.y, d4.y);
        PPIX(t4.z, m4.z, s4.z, a4.z, b4.z, c4.z, d4.z);
        PPIX(t4.w, m4.w, s4.w, a4.w, b4.w, c4.w, d4.w);
#undef PPIX
    }
    {
        float v = wred(r_at); if (lane == 0) atomicAdd(&sred[0], v);
        v = wred(r_bt); if (lane == 0) atomicAdd(&sred[1], v);
        v = wred(r_ct); if (lane == 0) atomicAdd(&sred[2], v);
        v = wred(r_ag); if (lane == 0) atomicAdd(&sred[3], v);
    }
    __syncthreads();
    if (tid < 4) {
        int gi = (tid == 0) ? (OFF_AT + b) : (tid == 1) ? (OFF_BT + b)
               : (tid == 2) ? (OFF_CT + b) : (OFF_AGGR + b);
        atomicAdd(&wsf[gi], sred[tid]);
    }
}

// ---------------- K4: final assembly ----------------
__global__ void k_final(unsigned* __restrict__ wsu, float* __restrict__ out) {
    float* wsf = (float*)wsu;
    __shared__ float lt[NB], lk[NB], la[NB], ld[NB];
    int b = threadIdx.x;
    if (b < NB) {
        const float S = 1e-3f;
        float a = wsf[OFF_AT + b] + S, bb = wsf[OFF_BT + b] + S, c = wsf[OFF_CT + b] + S;
        lt[b] = 1.f - 2.f * a / (bb + c);
        a = wsf[OFF_AK + b] + S; bb = wsf[OFF_BK + b] + S; c = wsf[OFF_CK + b] + S;
        lk[b] = 1.f - 2.f * a / (bb + c);
        int nval = (int)wsu[OFF_NVAL + b];
        la[b] = (nval > 0) ? wsf[OFF_AGGR + b] / fmaxf((float)nval, 1.f) : 0.f;
        ld[b] = wsf[OFF_DISCR + b];
    }
    __syncthreads();
    if (b == 0) {
        float st = 0, sk = 0, sa = 0, sd = 0;
        for (int i = 0; i < NB; i++) { st += lt[i]; sk += lk[i]; sa += la[i]; sd += ld[i]; }
        out[0] = st / NB;
        out[1] = 0.5f * sk / NB;
        out[2] = 0.25f * sa / NB;
        out[3] = 0.25f * sd / NB;
    }
}

extern "C" void kernel_launch(void* const* d_in, const int* in_sizes, int n_in,
                              void* d_out, int out_size, void* d_ws, size_t ws_size,
                              hipStream_t stream) {
    const float* preds = (const float*)d_in[0];
    const int* text = (const int*)d_in[1];
    const int* kern = (const int*)d_in[2];
    const int* mask = (const int*)d_in[3];
    unsigned* wsu = (unsigned*)d_ws;
    float* out = (float*)d_out;

    const int do_compact = (ws_size >= WS_FULL_BYTES) ? 1 : 0;

    hipMemsetAsync(d_ws, 0, (size_t)ZERO_WORDS * 4, stream);

    dim3 grid(BPB, NB);
    k_stats<<<grid, NTHR, 0, stream>>>(preds, text, kern, mask, wsu, do_compact);
    k_sel<<<NB, NTHR, 0, stream>>>(wsu, do_compact);
    if (!do_compact) {
        dim3 hgrid(128, NB);
        for (int pass = 0; pass < 4; pass++) {
            k_hist<<<hgrid, NTHR, 0, stream>>>(preds, text, wsu, pass);
            k_select<<<1, 64, 0, stream>>>(wsu, pass);
        }
    }
    k_pix<<<grid, NTHR, 0, stream>>>(preds, text, mask, wsu);
    k_final<<<1, 64, 0, stream>>>(wsu, out);
}

// Round 4
// 364.879 us; speedup vs baseline: 1.4733x; 1.4733x over previous
//
#include <hip/hip_runtime.h>
#include <math.h>

#define HW (512 * 512)
#define NB 16
#define NTHR 256
#define GX 256          // blocks per batch: 256 blocks * 256 thr * 4 px = HW
#define REP 16          // accumulator replicas to spread hot atomic lines

// ---- workspace layout (4-byte words) ----
// zeroed region:
#define OFF_ACC    0                           // f [REP][NB*52]  k_stats accum
#define ACC_STRIDE (NB * 52)                   // 832
#define OFF_PACC   (OFF_ACC + REP * ACC_STRIDE)    // f [REP][NB*4] k_pix accum
#define PACC_STRIDE (NB * 4)                   // 64
#define OFF_HISTFB (OFF_PACC + REP * PACC_STRIDE)  // u [4][16][256] fallback hists
#define ZERO_WORDS (OFF_HISTFB + 4 * 16 * 256)
// non-zeroed region (written unconditionally before read):
#define OFF_TBL    ZERO_WORDS                  // f [16][9][5] rows0..8={a0..a3,w}
#define OFF_THR    (OFF_TBL + 16 * 45)         // f [16]
#define OFF_FB     (OFF_THR + 16)              // u [16]
#define OFF_NVAL   (OFF_FB + 16)               // u [16]
#define OFF_DISCR  (OFF_NVAL + 16)             // f [16]
#define OFF_PREFIX (OFF_DISCR + 16)            // u [16] fallback select state
#define OFF_KKC    (OFF_PREFIX + 16)           // u [16]
#define OFF_NEGC   (OFF_KKC + 16)              // u [16]
#define OFF_CNTS   (OFF_NEGC + 16)             // u [NB][1024] per-wave seg counts
#define OFF_KEYS   (OFF_CNTS + NB * 1024)      // u [NB][HW] seg-compacted neg keys
#define WS_FULL_BYTES ((size_t)(OFF_KEYS + NB * HW) * 4)

// acc value indices: 0-7 kcnt, 8-15 tcnt, 16-47 ksum, 48 pos, 49 ak, 50 bk, 51 ck

__device__ __forceinline__ unsigned fmap(float f) {
    unsigned u = __float_as_uint(f);
    return (u & 0x80000000u) ? ~u : (u | 0x80000000u);
}
__device__ __forceinline__ float funmap(unsigned u) {
    return (u & 0x80000000u) ? __uint_as_float(u & 0x7FFFFFFFu)
                             : __uint_as_float(~u);
}
__device__ __forceinline__ float wred(float x) {
#pragma unroll
    for (int o = 32; o; o >>= 1) x += __shfl_xor(x, o);
    return x;
}
__device__ __forceinline__ unsigned wredu(unsigned x) {
#pragma unroll
    for (int o = 32; o; o >>= 1) x += __shfl_xor(x, o);
    return x;
}

// ---------------- K1: one-shot stats + kernel-dice + segment compaction ----------------
// No atomics and no returning memory ops in the hot path: compaction goes to a
// deterministic per-wave segment (round-3 post-mortem: the per-iter returning
// atomicAdd on one shared cache line serialized the whole grid at ~30cyc/op).
__global__ __launch_bounds__(NTHR, 2) void k_stats(const float* __restrict__ preds,
                        const int* __restrict__ text,
                        const int* __restrict__ kern,
                        const int* __restrict__ mask,
                        unsigned* __restrict__ wsu, int do_compact) {
    float* wsf = (float*)wsu;
    const int b = blockIdx.y;
    const int tid = threadIdx.x;
    const int lane = tid & 63;
    const unsigned long long lmask = (1ull << lane) - 1ull;
    __shared__ float sacc[52];
    if (tid < 52) sacc[tid] = 0.f;
    __syncthreads();

    const int base = blockIdx.x * (NTHR * 4) + tid * 4;
    const int* tb = text + b * HW;
    const int* kb = kern + b * HW;
    const int* mb = mask + b * HW;
    const float* p0 = preds + (size_t)(b * 6 + 0) * HW;
    const float* p1 = preds + (size_t)(b * 6 + 1) * HW;
    const float* e0 = preds + (size_t)(b * 6 + 2) * HW;
    const float* e1 = e0 + HW;
    const float* e2 = e0 + 2 * HW;
    const float* e3 = e0 + 3 * HW;

    const int4 t4 = *(const int4*)(tb + base);
    const int4 k4 = *(const int4*)(kb + base);
    const int4 m4 = *(const int4*)(mb + base);
    const float4 s4 = *(const float4*)(p0 + base);
    const float4 q4 = *(const float4*)(p1 + base);
    const float4 a4 = *(const float4*)(e0 + base);
    const float4 b4 = *(const float4*)(e1 + base);
    const float4 c4 = *(const float4*)(e2 + base);
    const float4 d4 = *(const float4*)(e3 + base);

    float ks[32];
#pragma unroll
    for (int i = 0; i < 32; i++) ks[i] = 0.f;
    float r_ak = 0.f, r_bk = 0.f, r_ck = 0.f;
    unsigned kcW[8] = {0, 0, 0, 0, 0, 0, 0, 0};
    unsigned tcW[8] = {0, 0, 0, 0, 0, 0, 0, 0};
    unsigned posW = 0;

#define PIX(T, K, M, Q, A, B, C, D) do {                                     \
        bool pos_ = (T) > 0, mp_ = (M) > 0;                                  \
        float sm_ = (pos_ && mp_) ? 1.f : 0.f;                               \
        float sg_ = 1.f / (1.f + expf(-(Q)));                                \
        float ik_ = ((K) > 0) ? 1.f : 0.f;                                   \
        r_ak += sm_ * sg_ * ik_;                                             \
        r_bk += sm_ * sg_ * sg_;                                             \
        r_ck += sm_ * ik_;                                                   \
        posW += (unsigned)__popcll(__ballot(pos_ && mp_));                   \
        _Pragma("unroll")                                                    \
        for (int i_ = 0; i_ < 8; i_++) {                                     \
            bool hit_ = ((K) == i_ + 1);                                     \
            kcW[i_] += (unsigned)__popcll(__ballot(hit_));                   \
            tcW[i_] += (unsigned)__popcll(__ballot((T) == i_ + 1));          \
            float h_ = hit_ ? 1.f : 0.f;                                     \
            ks[i_ * 4 + 0] += h_ * (A);                                      \
            ks[i_ * 4 + 1] += h_ * (B);                                      \
            ks[i_ * 4 + 2] += h_ * (C);                                      \
            ks[i_ * 4 + 3] += h_ * (D);                                      \
        }                                                                    \
    } while (0)

    PIX(t4.x, k4.x, m4.x, q4.x, a4.x, b4.x, c4.x, d4.x);
    PIX(t4.y, k4.y, m4.y, q4.y, a4.y, b4.y, c4.y, d4.y);
    PIX(t4.z, k4.z, m4.z, q4.z, a4.z, b4.z, c4.z, d4.z);
    PIX(t4.w, k4.w, m4.w, q4.w, a4.w, b4.w, c4.w, d4.w);
#undef PIX

    // ---- deterministic segment compaction (no atomics) ----
    const unsigned long long m0 = __ballot(t4.x == 0);
    const unsigned long long m1 = __ballot(t4.y == 0);
    const unsigned long long m2 = __ballot(t4.z == 0);
    const unsigned long long m3 = __ballot(t4.w == 0);
    const unsigned c0 = (unsigned)__popcll(m0), c1 = (unsigned)__popcll(m1);
    const unsigned c2 = (unsigned)__popcll(m2), c3 = (unsigned)__popcll(m3);
    const unsigned tot = c0 + c1 + c2 + c3;
    const int seg = blockIdx.x * 4 + (tid >> 6);
    if (lane == 0) wsu[OFF_CNTS + b * 1024 + seg] = tot;
    if (do_compact) {
        unsigned* keys = wsu + OFF_KEYS + (size_t)b * HW + (size_t)seg * 256;
        if (t4.x == 0) keys[(unsigned)__popcll(m0 & lmask)] = fmap(s4.x);
        if (t4.y == 0) keys[c0 + (unsigned)__popcll(m1 & lmask)] = fmap(s4.y);
        if (t4.z == 0) keys[c0 + c1 + (unsigned)__popcll(m2 & lmask)] = fmap(s4.z);
        if (t4.w == 0) keys[c0 + c1 + c2 + (unsigned)__popcll(m3 & lmask)] = fmap(s4.w);
    }

    // ---- epilogue: wave butterfly -> LDS -> one replica atomic per value ----
#pragma unroll
    for (int i = 0; i < 32; i++) {
        float v = wred(ks[i]);
        if (lane == 0) atomicAdd(&sacc[16 + i], v);
    }
    {
        float v = wred(r_ak); if (lane == 0) atomicAdd(&sacc[49], v);
        v = wred(r_bk); if (lane == 0) atomicAdd(&sacc[50], v);
        v = wred(r_ck); if (lane == 0) atomicAdd(&sacc[51], v);
    }
    if (lane == 0) {
#pragma unroll
        for (int i = 0; i < 8; i++) {
            atomicAdd(&sacc[i], (float)kcW[i]);
            atomicAdd(&sacc[8 + i], (float)tcW[i]);
        }
        atomicAdd(&sacc[48], (float)posW);
    }
    __syncthreads();
    if (tid < 52) {
        const int rep = blockIdx.x & (REP - 1);
        atomicAdd(&wsf[OFF_ACC + rep * ACC_STRIDE + b * 52 + tid], sacc[tid]);
    }
}

// ---------------- K2: setup + segment-based 4-pass radix select ----------------
__global__ void k_sel(unsigned* __restrict__ wsu, int do_select) {
    float* wsf = (float*)wsu;
    const int b = blockIdx.x;
    const int tid = threadIdx.x;   // 1024 threads; tid == segment id
    const int lane = tid & 63;
    __shared__ float s_acc[52];
    __shared__ float s_avg[8][4];
    __shared__ int s_valid[8];
    __shared__ unsigned s_hist[256];
    __shared__ unsigned s_negtot;
    __shared__ unsigned s_kk, s_prefix;

    if (tid < 52) {
        float v = 0.f;
#pragma unroll
        for (int r = 0; r < REP; r++) v += wsf[OFF_ACC + r * ACC_STRIDE + b * 52 + tid];
        s_acc[tid] = v;
    }
    if (tid == 0) s_negtot = 0u;
    __syncthreads();

    const unsigned myc = wsu[OFF_CNTS + b * 1024 + tid];
    {
        unsigned cw = wredu(myc);
        if (lane == 0) atomicAdd(&s_negtot, cw);
    }
    if (tid < 8) {
        float kcf = s_acc[tid];
        float tcf = s_acc[8 + tid];
        int valid = (kcf > 0.f && tcf > 0.f) ? 1 : 0;
        float inv = 1.f / fmaxf(kcf, 1.f);
        float w = valid ? 1.f / fmaxf(tcf, 1.f) : 0.f;
#pragma unroll
        for (int c = 0; c < 4; c++) {
            float a = s_acc[16 + tid * 4 + c] * inv;
            s_avg[tid][c] = a;
            wsf[OFF_TBL + b * 45 + (tid + 1) * 5 + c] = a;
        }
        s_valid[tid] = valid;
        wsf[OFF_TBL + b * 45 + (tid + 1) * 5 + 4] = w;
    }
    if (tid >= 8 && tid < 13) wsf[OFF_TBL + b * 45 + (tid - 8)] = 0.f;  // bg row
    __syncthreads();
    if (tid == 0) {
        int nval = 0;
        for (int i = 0; i < 8; i++) nval += s_valid[i];
        float L = 0.f;
        for (int i = 0; i < 8; i++)
            for (int j = i + 1; j < 8; j++)
                if (s_valid[i] && s_valid[j]) {
                    float sq = 0.f;
                    for (int c = 0; c < 4; c++) {
                        float d = s_avg[i][c] - s_avg[j][c];
                        sq += d * d;
                    }
                    float h = fmaxf(3.0f - sqrtf(sq), 0.f);
                    L += log1pf(h * h);
                }
        wsf[OFF_DISCR + b] = (nval > 1) ? L / fmaxf((float)(nval * (nval - 1)), 1.f) : 0.f;
        wsu[OFF_NVAL + b] = (unsigned)nval;
        unsigned pos = (unsigned)s_acc[48];
        unsigned neg = s_negtot;
        wsu[OFF_NEGC + b] = neg;
        unsigned nn = min(pos * 3u, neg);
        int fb = (pos == 0u || nn == 0u) ? 1 : 0;
        wsu[OFF_FB + b] = (unsigned)fb;
        s_kk = fb ? 0u : nn;
        s_prefix = 0u;
        wsu[OFF_KKC + b] = fb ? 0u : nn;   // fallback path state
        wsu[OFF_PREFIX + b] = 0u;
        wsf[OFF_THR + b] = 0.f;
    }
    __syncthreads();
    if (!do_select) return;
    if (s_kk == 0u) return;                 // uniform: fb case
    const unsigned* keys = wsu + OFF_KEYS + (size_t)b * HW + (size_t)tid * 256;
    unsigned prefix = 0u;
    for (int pass = 0; pass < 4; pass++) {
        const int shift = 24 - 8 * pass;
        const unsigned fmask = (pass == 0) ? 0u : (0xFFFFFFFFu << (shift + 8));
        if (tid < 256) s_hist[tid] = 0u;
        __syncthreads();
        for (unsigned i = 0; i < myc; i++) {
            unsigned key = keys[i];
            if ((key & fmask) == prefix) atomicAdd(&s_hist[(key >> shift) & 255u], 1u);
        }
        __syncthreads();
        if (tid == 0) {
            unsigned k2 = s_kk;
            for (int bin = 255; bin >= 0; --bin) {
                unsigned c = s_hist[bin];
                if (k2 <= c) { s_prefix = prefix | (((unsigned)bin) << shift); s_kk = k2; break; }
                k2 -= c;
            }
        }
        __syncthreads();
        prefix = s_prefix;
    }
    if (tid == 0) wsf[OFF_THR + b] = funmap(prefix);
}

// ---------------- fallback radix select over raw data (only if ws too small) ----------------
__global__ void k_hist(const float* __restrict__ preds, const int* __restrict__ text,
                       unsigned* __restrict__ wsu, int pass) {
    const int b = blockIdx.y;
    const int tid = threadIdx.x;
    __shared__ unsigned h[256];
    h[tid] = 0u;
    __syncthreads();
    const unsigned prefix = wsu[OFF_PREFIX + b];
    const int shift = 24 - 8 * pass;
    const unsigned fmask = (pass == 0) ? 0u : (0xFFFFFFFFu << (shift + 8));
    const int* tb = text + b * HW;
    const float* pt = preds + (size_t)(b * 6) * HW;
    for (int p = blockIdx.x * NTHR + tid; p < HW; p += gridDim.x * NTHR) {
        if (tb[p] == 0) {
            unsigned key = fmap(pt[p]);
            if ((key & fmask) == prefix) atomicAdd(&h[(key >> shift) & 255u], 1u);
        }
    }
    __syncthreads();
    if (h[tid]) atomicAdd(&wsu[OFF_HISTFB + pass * 4096 + b * 256 + tid], h[tid]);
}
__global__ void k_select(unsigned* __restrict__ wsu, int pass) {
    int b = threadIdx.x;
    if (b >= NB) return;
    float* wsf = (float*)wsu;
    unsigned k = wsu[OFF_KKC + b];
    unsigned prefix = wsu[OFF_PREFIX + b];
    const int shift = 24 - 8 * pass;
    const unsigned* h = &wsu[OFF_HISTFB + pass * 4096 + b * 256];
    if (k > 0) {
        for (int bin = 255; bin >= 0; --bin) {
            unsigned c = h[bin];
            if (k <= c) { prefix |= ((unsigned)bin) << shift; break; }
            k -= c;
        }
        wsu[OFF_KKC + b] = k;
        wsu[OFF_PREFIX + b] = prefix;
    }
    if (pass == 3) wsf[OFF_THR + b] = funmap(prefix);
}

// ---------------- K3: one-shot fused aggregation + OHEM text-dice ----------------
__global__ __launch_bounds__(NTHR, 2) void k_pix(const float* __restrict__ preds,
                      const int* __restrict__ text,
                      const int* __restrict__ mask,
                      unsigned* __restrict__ wsu) {
    float* wsf = (float*)wsu;
    const int b = blockIdx.y;
    const int tid = threadIdx.x;
    const int lane = tid & 63;
    __shared__ float stbl[45];
    __shared__ float sred[4];
    __shared__ float sthr;
    __shared__ unsigned sfb;
    if (tid < 45) stbl[tid] = wsf[OFF_TBL + b * 45 + tid];
    if (tid < 4) sred[tid] = 0.f;
    if (tid == 0) { sthr = wsf[OFF_THR + b]; sfb = wsu[OFF_FB + b]; }
    __syncthreads();
    const float thr = sthr;
    const bool fb = sfb != 0u;
    float r_at = 0.f, r_bt = 0.f, r_ct = 0.f, r_ag = 0.f;
    const int base = blockIdx.x * (NTHR * 4) + tid * 4;
    const int* tb = text + b * HW;
    const int* mb = mask + b * HW;
    const float* p0 = preds + (size_t)(b * 6) * HW;
    const float* e0 = preds + (size_t)(b * 6 + 2) * HW;
    const float* e1 = e0 + HW;
    const float* e2 = e0 + 2 * HW;
    const float* e3 = e0 + 3 * HW;
    const int4 t4 = *(const int4*)(tb + base);
    const int4 m4 = *(const int4*)(mb + base);
    const float4 s4 = *(const float4*)(p0 + base);
    const float4 a4 = *(const float4*)(e0 + base);
    const float4 b4 = *(const float4*)(e1 + base);
    const float4 c4 = *(const float4*)(e2 + base);
    const float4 d4 = *(const float4*)(e3 + base);

#define PPIX(T, M, S, A, B, C, D) do {                                       \
        bool pos_ = (T) > 0;                                                 \
        bool samp_ = fb ? ((M) > 0) : ((((S) >= thr) || pos_) && ((M) > 0)); \
        float sg_ = 1.f / (1.f + expf(-(S)));                                \
        float smf_ = samp_ ? 1.f : 0.f;                                      \
        float it_ = pos_ ? 1.f : 0.f;                                        \
        r_at += smf_ * sg_ * it_;                                            \
        r_bt += smf_ * sg_ * sg_;                                            \
        r_ct += smf_ * it_;                                                  \
        int t5_ = min((T), 8) * 5;                                           \
        float d0_ = (A) - stbl[t5_ + 0];                                     \
        float d1_ = (B) - stbl[t5_ + 1];                                     \
        float d2_ = (C) - stbl[t5_ + 2];                                     \
        float d3_ = (D) - stbl[t5_ + 3];                                     \
        float w_ = stbl[t5_ + 4];                                            \
        float sq_ = d0_ * d0_ + d1_ * d1_ + d2_ * d2_ + d3_ * d3_;           \
        float dist_ = sqrtf(sq_ + 1e-12f) - 0.5f;                            \
        float hp_ = fmaxf(dist_, 0.f);                                       \
        r_ag += w_ * log1pf(hp_ * hp_);                                      \
    } while (0)

    PPIX(t4.x, m4.x, s4.x, a4.x, b4.x, c4.x, d4.x);
    PPIX(t4.y, m4.y, s4.y, a4.y, b4.y, c4.y, d4.y);
    PPIX(t4.z, m4.z, s4.z, a4.z, b4.z, c4.z, d4.z);
    PPIX(t4.w, m4.w, s4.w, a4.w, b4.w, c4.w, d4.w);
#undef PPIX

    {
        float v = wred(r_at); if (lane == 0) atomicAdd(&sred[0], v);
        v = wred(r_bt); if (lane == 0) atomicAdd(&sred[1], v);
        v = wred(r_ct); if (lane == 0) atomicAdd(&sred[2], v);
        v = wred(r_ag); if (lane == 0) atomicAdd(&sred[3], v);
    }
    __syncthreads();
    if (tid < 4) {
        const int rep = blockIdx.x & (REP - 1);
        atomicAdd(&wsf[OFF_PACC + rep * PACC_STRIDE + b * 4 + tid], sred[tid]);
    }
}

// ---------------- K4: final assembly ----------------
__global__ void k_final(unsigned* __restrict__ wsu, float* __restrict__ out) {
    float* wsf = (float*)wsu;
    __shared__ float lt[NB], lk[NB], la[NB], ld[NB];
    int b = threadIdx.x;
    if (b < NB) {
        const float S = 1e-3f;
        float ak = 0.f, bk = 0.f, ck = 0.f, at = 0.f, bt = 0.f, ct = 0.f, ag = 0.f;
#pragma unroll
        for (int r = 0; r < REP; r++) {
            ak += wsf[OFF_ACC + r * ACC_STRIDE + b * 52 + 49];
            bk += wsf[OFF_ACC + r * ACC_STRIDE + b * 52 + 50];
            ck += wsf[OFF_ACC + r * ACC_STRIDE + b * 52 + 51];
            at += wsf[OFF_PACC + r * PACC_STRIDE + b * 4 + 0];
            bt += wsf[OFF_PACC + r * PACC_STRIDE + b * 4 + 1];
            ct += wsf[OFF_PACC + r * PACC_STRIDE + b * 4 + 2];
            ag += wsf[OFF_PACC + r * PACC_STRIDE + b * 4 + 3];
        }
        lt[b] = 1.f - 2.f * (at + S) / ((bt + S) + (ct + S));
        lk[b] = 1.f - 2.f * (ak + S) / ((bk + S) + (ck + S));
        int nval = (int)wsu[OFF_NVAL + b];
        la[b] = (nval > 0) ? ag / fmaxf((float)nval, 1.f) : 0.f;
        ld[b] = wsf[OFF_DISCR + b];
    }
    __syncthreads();
    if (b == 0) {
        float st = 0, sk = 0, sa = 0, sd = 0;
        for (int i = 0; i < NB; i++) { st += lt[i]; sk += lk[i]; sa += la[i]; sd += ld[i]; }
        out[0] = st / NB;
        out[1] = 0.5f * sk / NB;
        out[2] = 0.25f * sa / NB;
        out[3] = 0.25f * sd / NB;
    }
}

extern "C" void kernel_launch(void* const* d_in, const int* in_sizes, int n_in,
                              void* d_out, int out_size, void* d_ws, size_t ws_size,
                              hipStream_t stream) {
    const float* preds = (const float*)d_in[0];
    const int* text = (const int*)d_in[1];
    const int* kern = (const int*)d_in[2];
    const int* mask = (const int*)d_in[3];
    unsigned* wsu = (unsigned*)d_ws;
    float* out = (float*)d_out;

    const int do_compact = (ws_size >= WS_FULL_BYTES) ? 1 : 0;

    hipMemsetAsync(d_ws, 0, (size_t)ZERO_WORDS * 4, stream);

    dim3 grid(GX, NB);
    k_stats<<<grid, NTHR, 0, stream>>>(preds, text, kern, mask, wsu, do_compact);
    k_sel<<<NB, 1024, 0, stream>>>(wsu, do_compact);
    if (!do_compact) {
        dim3 hgrid(128, NB);
        for (int pass = 0; pass < 4; pass++) {
            k_hist<<<hgrid, NTHR, 0, stream>>>(preds, text, wsu, pass);
            k_select<<<1, 64, 0, stream>>>(wsu, pass);
        }
    }
    k_pix<<<grid, NTHR, 0, stream>>>(preds, text, mask, wsu);
    k_final<<<1, 64, 0, stream>>>(wsu, out);
}

// Round 5
// 260.337 us; speedup vs baseline: 2.0649x; 1.4016x over previous
//
#include <hip/hip_runtime.h>
#include <math.h>

#define HW (512 * 512)
#define NB 16
#define NTHR 256
#define GX 256          // blocks per batch: 256 blocks * 256 thr * 4 px = HW
#define REP 16          // accumulator replicas to spread hot atomic lines

// ---- workspace layout (4-byte words) ----
// zeroed region:
#define OFF_ACC    0                           // f [REP][NB*52]  k_stats accum
#define ACC_STRIDE (NB * 52)                   // 832
#define OFF_PACC   (OFF_ACC + REP * ACC_STRIDE)    // f [REP][NB*4] k_pix accum
#define PACC_STRIDE (NB * 4)                   // 64
#define OFF_HISTFB (OFF_PACC + REP * PACC_STRIDE)  // u [4][16][256] fallback hists
#define OFF_NEGMX  (OFF_HISTFB + 4 * 16 * 256) // u [NB][REP]: max(~key) over negs
#define ZERO_WORDS (OFF_NEGMX + NB * REP)
// non-zeroed region (written unconditionally before read):
#define OFF_TBL    ZERO_WORDS                  // f [16][9][5] rows0..8={a0..a3,w}
#define OFF_THR    (OFF_TBL + 16 * 45)         // f [16]
#define OFF_FB     (OFF_THR + 16)              // u [16]
#define OFF_NVAL   (OFF_FB + 16)               // u [16]
#define OFF_DISCR  (OFF_NVAL + 16)             // f [16]
#define OFF_PREFIX (OFF_DISCR + 16)            // u [16] fallback select state
#define OFF_KKC    (OFF_PREFIX + 16)           // u [16]
#define OFF_NEGC   (OFF_KKC + 16)              // u [16]
#define OFF_CNTS   (OFF_NEGC + 16)             // u [NB][1024] per-wave seg counts
#define OFF_KEYS   (OFF_CNTS + NB * 1024)      // u [NB][HW] seg-compacted neg keys
#define WS_FULL_BYTES ((size_t)(OFF_KEYS + NB * HW) * 4)

// acc value indices: 0-7 kcnt, 8-15 tcnt, 16-47 ksum, 48 pos, 49 ak, 50 bk, 51 ck

__device__ __forceinline__ unsigned fmap(float f) {
    unsigned u = __float_as_uint(f);
    return (u & 0x80000000u) ? ~u : (u | 0x80000000u);
}
__device__ __forceinline__ float funmap(unsigned u) {
    return (u & 0x80000000u) ? __uint_as_float(u & 0x7FFFFFFFu)
                             : __uint_as_float(~u);
}
__device__ __forceinline__ float wred(float x) {
#pragma unroll
    for (int o = 32; o; o >>= 1) x += __shfl_xor(x, o);
    return x;
}
__device__ __forceinline__ unsigned wredu(unsigned x) {
#pragma unroll
    for (int o = 32; o; o >>= 1) x += __shfl_xor(x, o);
    return x;
}
__device__ __forceinline__ unsigned wredumax(unsigned x) {
#pragma unroll
    for (int o = 32; o; o >>= 1) x = max(x, (unsigned)__shfl_xor((int)x, o));
    return x;
}

// ---------------- K1: one-shot stats + kernel-dice + segment compaction ----------------
// No atomics/returning memory ops in the hot path (round-3 lesson). Also feeds
// the fast OHEM path: per-batch min negative key via fire-and-forget atomicMax
// of ~key into REP replicas (round-4 lesson: the 16-block LDS-histogram radix
// select was 131us of latency + 154k LDS bank conflicts).
__global__ __launch_bounds__(NTHR, 2) void k_stats(const float* __restrict__ preds,
                        const int* __restrict__ text,
                        const int* __restrict__ kern,
                        const int* __restrict__ mask,
                        unsigned* __restrict__ wsu, int do_compact) {
    float* wsf = (float*)wsu;
    const int b = blockIdx.y;
    const int tid = threadIdx.x;
    const int lane = tid & 63;
    const unsigned long long lmask = (1ull << lane) - 1ull;
    __shared__ float sacc[52];
    if (tid < 52) sacc[tid] = 0.f;
    __syncthreads();

    const int base = blockIdx.x * (NTHR * 4) + tid * 4;
    const int* tb = text + b * HW;
    const int* kb = kern + b * HW;
    const int* mb = mask + b * HW;
    const float* p0 = preds + (size_t)(b * 6 + 0) * HW;
    const float* p1 = preds + (size_t)(b * 6 + 1) * HW;
    const float* e0 = preds + (size_t)(b * 6 + 2) * HW;
    const float* e1 = e0 + HW;
    const float* e2 = e0 + 2 * HW;
    const float* e3 = e0 + 3 * HW;

    const int4 t4 = *(const int4*)(tb + base);
    const int4 k4 = *(const int4*)(kb + base);
    const int4 m4 = *(const int4*)(mb + base);
    const float4 s4 = *(const float4*)(p0 + base);
    const float4 q4 = *(const float4*)(p1 + base);
    const float4 a4 = *(const float4*)(e0 + base);
    const float4 b4 = *(const float4*)(e1 + base);
    const float4 c4 = *(const float4*)(e2 + base);
    const float4 d4 = *(const float4*)(e3 + base);

    float ks[32];
#pragma unroll
    for (int i = 0; i < 32; i++) ks[i] = 0.f;
    float r_ak = 0.f, r_bk = 0.f, r_ck = 0.f;
    unsigned kcW[8] = {0, 0, 0, 0, 0, 0, 0, 0};
    unsigned tcW[8] = {0, 0, 0, 0, 0, 0, 0, 0};
    unsigned posW = 0;

#define PIX(T, K, M, Q, A, B, C, D) do {                                     \
        bool pos_ = (T) > 0, mp_ = (M) > 0;                                  \
        float sm_ = (pos_ && mp_) ? 1.f : 0.f;                               \
        float sg_ = 1.f / (1.f + expf(-(Q)));                                \
        float ik_ = ((K) > 0) ? 1.f : 0.f;                                   \
        r_ak += sm_ * sg_ * ik_;                                             \
        r_bk += sm_ * sg_ * sg_;                                             \
        r_ck += sm_ * ik_;                                                   \
        posW += (unsigned)__popcll(__ballot(pos_ && mp_));                   \
        _Pragma("unroll")                                                    \
        for (int i_ = 0; i_ < 8; i_++) {                                     \
            bool hit_ = ((K) == i_ + 1);                                     \
            kcW[i_] += (unsigned)__popcll(__ballot(hit_));                   \
            tcW[i_] += (unsigned)__popcll(__ballot((T) == i_ + 1));          \
            float h_ = hit_ ? 1.f : 0.f;                                     \
            ks[i_ * 4 + 0] += h_ * (A);                                      \
            ks[i_ * 4 + 1] += h_ * (B);                                      \
            ks[i_ * 4 + 2] += h_ * (C);                                      \
            ks[i_ * 4 + 3] += h_ * (D);                                      \
        }                                                                    \
    } while (0)

    PIX(t4.x, k4.x, m4.x, q4.x, a4.x, b4.x, c4.x, d4.x);
    PIX(t4.y, k4.y, m4.y, q4.y, a4.y, b4.y, c4.y, d4.y);
    PIX(t4.z, k4.z, m4.z, q4.z, a4.z, b4.z, c4.z, d4.z);
    PIX(t4.w, k4.w, m4.w, q4.w, a4.w, b4.w, c4.w, d4.w);
#undef PIX

    // ---- deterministic segment compaction (no atomics) ----
    const unsigned long long m0 = __ballot(t4.x == 0);
    const unsigned long long m1 = __ballot(t4.y == 0);
    const unsigned long long m2 = __ballot(t4.z == 0);
    const unsigned long long m3 = __ballot(t4.w == 0);
    const unsigned c0 = (unsigned)__popcll(m0), c1 = (unsigned)__popcll(m1);
    const unsigned c2 = (unsigned)__popcll(m2), c3 = (unsigned)__popcll(m3);
    const unsigned tot = c0 + c1 + c2 + c3;
    const int seg = blockIdx.x * 4 + (tid >> 6);
    if (lane == 0) wsu[OFF_CNTS + b * 1024 + seg] = tot;
    if (do_compact) {
        unsigned* keys = wsu + OFF_KEYS + (size_t)b * HW + (size_t)seg * 256;
        if (t4.x == 0) keys[(unsigned)__popcll(m0 & lmask)] = fmap(s4.x);
        if (t4.y == 0) keys[c0 + (unsigned)__popcll(m1 & lmask)] = fmap(s4.y);
        if (t4.z == 0) keys[c0 + c1 + (unsigned)__popcll(m2 & lmask)] = fmap(s4.z);
        if (t4.w == 0) keys[c0 + c1 + c2 + (unsigned)__popcll(m3 & lmask)] = fmap(s4.w);
    }
    // ---- min negative score via max(~key), zero-init replicas ----
    {
        unsigned mk = 0u;
        if (t4.x == 0) mk = max(mk, ~fmap(s4.x));
        if (t4.y == 0) mk = max(mk, ~fmap(s4.y));
        if (t4.z == 0) mk = max(mk, ~fmap(s4.z));
        if (t4.w == 0) mk = max(mk, ~fmap(s4.w));
        mk = wredumax(mk);
        if (lane == 0 && mk)
            atomicMax(&wsu[OFF_NEGMX + b * REP + (blockIdx.x & (REP - 1))], mk);
    }

    // ---- epilogue: wave butterfly -> LDS -> one replica atomic per value ----
#pragma unroll
    for (int i = 0; i < 32; i++) {
        float v = wred(ks[i]);
        if (lane == 0) atomicAdd(&sacc[16 + i], v);
    }
    {
        float v = wred(r_ak); if (lane == 0) atomicAdd(&sacc[49], v);
        v = wred(r_bk); if (lane == 0) atomicAdd(&sacc[50], v);
        v = wred(r_ck); if (lane == 0) atomicAdd(&sacc[51], v);
    }
    if (lane == 0) {
#pragma unroll
        for (int i = 0; i < 8; i++) {
            atomicAdd(&sacc[i], (float)kcW[i]);
            atomicAdd(&sacc[8 + i], (float)tcW[i]);
        }
        atomicAdd(&sacc[48], (float)posW);
    }
    __syncthreads();
    if (tid < 52) {
        const int rep = blockIdx.x & (REP - 1);
        atomicAdd(&wsf[OFF_ACC + rep * ACC_STRIDE + b * 52 + tid], sacc[tid]);
    }
}

// ---------------- K2: setup + OHEM threshold ----------------
// Fast path: neg_num == neg  =>  threshold = min negative score (pure reduction,
// already computed by k_stats). Radix select only runs when 3*pos < neg.
__global__ void k_sel(unsigned* __restrict__ wsu, int do_select) {
    float* wsf = (float*)wsu;
    const int b = blockIdx.x;
    const int tid = threadIdx.x;   // 1024 threads; tid == segment id
    const int lane = tid & 63;
    __shared__ float s_acc[52];
    __shared__ float s_avg[8][4];
    __shared__ int s_valid[8];
    __shared__ unsigned s_hist[256];
    __shared__ unsigned s_negtot;
    __shared__ unsigned s_kk, s_prefix;

    if (tid < 52) {
        float v = 0.f;
#pragma unroll
        for (int r = 0; r < REP; r++) v += wsf[OFF_ACC + r * ACC_STRIDE + b * 52 + tid];
        s_acc[tid] = v;
    }
    if (tid == 0) s_negtot = 0u;
    __syncthreads();

    const unsigned myc = wsu[OFF_CNTS + b * 1024 + tid];
    {
        unsigned cw = wredu(myc);
        if (lane == 0) atomicAdd(&s_negtot, cw);
    }
    if (tid < 8) {
        float kcf = s_acc[tid];
        float tcf = s_acc[8 + tid];
        int valid = (kcf > 0.f && tcf > 0.f) ? 1 : 0;
        float inv = 1.f / fmaxf(kcf, 1.f);
        float w = valid ? 1.f / fmaxf(tcf, 1.f) : 0.f;
#pragma unroll
        for (int c = 0; c < 4; c++) {
            float a = s_acc[16 + tid * 4 + c] * inv;
            s_avg[tid][c] = a;
            wsf[OFF_TBL + b * 45 + (tid + 1) * 5 + c] = a;
        }
        s_valid[tid] = valid;
        wsf[OFF_TBL + b * 45 + (tid + 1) * 5 + 4] = w;
    }
    if (tid >= 8 && tid < 13) wsf[OFF_TBL + b * 45 + (tid - 8)] = 0.f;  // bg row
    __syncthreads();
    if (tid == 0) {
        int nval = 0;
        for (int i = 0; i < 8; i++) nval += s_valid[i];
        float L = 0.f;
        for (int i = 0; i < 8; i++)
            for (int j = i + 1; j < 8; j++)
                if (s_valid[i] && s_valid[j]) {
                    float sq = 0.f;
                    for (int c = 0; c < 4; c++) {
                        float d = s_avg[i][c] - s_avg[j][c];
                        sq += d * d;
                    }
                    float h = fmaxf(3.0f - sqrtf(sq), 0.f);
                    L += log1pf(h * h);
                }
        wsf[OFF_DISCR + b] = (nval > 1) ? L / fmaxf((float)(nval * (nval - 1)), 1.f) : 0.f;
        wsu[OFF_NVAL + b] = (unsigned)nval;
        unsigned pos = (unsigned)s_acc[48];
        unsigned neg = s_negtot;
        wsu[OFF_NEGC + b] = neg;
        unsigned nn = min(pos * 3u, neg);
        int fb = (pos == 0u || nn == 0u) ? 1 : 0;
        wsu[OFF_FB + b] = (unsigned)fb;
        wsu[OFF_KKC + b] = fb ? 0u : nn;   // fallback path state
        wsu[OFF_PREFIX + b] = 0u;
        wsf[OFF_THR + b] = 0.f;
        unsigned kk = fb ? 0u : nn;
        if (!fb && nn == neg) {
            // fast path: threshold = min negative score
            unsigned mx = 0u;
#pragma unroll
            for (int r = 0; r < REP; r++) mx = max(mx, wsu[OFF_NEGMX + b * REP + r]);
            wsf[OFF_THR + b] = funmap(~mx);
            kk = 0u;                        // skip radix
        }
        s_kk = kk;
        s_prefix = 0u;
    }
    __syncthreads();
    if (!do_select) return;
    if (s_kk == 0u) return;                 // uniform: fb or fast path
    const unsigned* keys = wsu + OFF_KEYS + (size_t)b * HW + (size_t)tid * 256;
    unsigned prefix = 0u;
    for (int pass = 0; pass < 4; pass++) {
        const int shift = 24 - 8 * pass;
        const unsigned fmask = (pass == 0) ? 0u : (0xFFFFFFFFu << (shift + 8));
        if (tid < 256) s_hist[tid] = 0u;
        __syncthreads();
        for (unsigned i = 0; i < myc; i++) {
            unsigned key = keys[i];
            if ((key & fmask) == prefix) atomicAdd(&s_hist[(key >> shift) & 255u], 1u);
        }
        __syncthreads();
        if (tid == 0) {
            unsigned k2 = s_kk;
            for (int bin = 255; bin >= 0; --bin) {
                unsigned c = s_hist[bin];
                if (k2 <= c) { s_prefix = prefix | (((unsigned)bin) << shift); s_kk = k2; break; }
                k2 -= c;
            }
        }
        __syncthreads();
        prefix = s_prefix;
    }
    if (tid == 0) wsf[OFF_THR + b] = funmap(prefix);
}

// ---------------- fallback radix select over raw data (only if ws too small) ----------------
__global__ void k_hist(const float* __restrict__ preds, const int* __restrict__ text,
                       unsigned* __restrict__ wsu, int pass) {
    const int b = blockIdx.y;
    const int tid = threadIdx.x;
    __shared__ unsigned h[256];
    h[tid] = 0u;
    __syncthreads();
    const unsigned prefix = wsu[OFF_PREFIX + b];
    const int shift = 24 - 8 * pass;
    const unsigned fmask = (pass == 0) ? 0u : (0xFFFFFFFFu << (shift + 8));
    const int* tb = text + b * HW;
    const float* pt = preds + (size_t)(b * 6) * HW;
    for (int p = blockIdx.x * NTHR + tid; p < HW; p += gridDim.x * NTHR) {
        if (tb[p] == 0) {
            unsigned key = fmap(pt[p]);
            if ((key & fmask) == prefix) atomicAdd(&h[(key >> shift) & 255u], 1u);
        }
    }
    __syncthreads();
    if (h[tid]) atomicAdd(&wsu[OFF_HISTFB + pass * 4096 + b * 256 + tid], h[tid]);
}
__global__ void k_select(unsigned* __restrict__ wsu, int pass) {
    int b = threadIdx.x;
    if (b >= NB) return;
    float* wsf = (float*)wsu;
    unsigned k = wsu[OFF_KKC + b];
    unsigned prefix = wsu[OFF_PREFIX + b];
    const int shift = 24 - 8 * pass;
    const unsigned* h = &wsu[OFF_HISTFB + pass * 4096 + b * 256];
    if (k > 0) {
        for (int bin = 255; bin >= 0; --bin) {
            unsigned c = h[bin];
            if (k <= c) { prefix |= ((unsigned)bin) << shift; break; }
            k -= c;
        }
        wsu[OFF_KKC + b] = k;
        wsu[OFF_PREFIX + b] = prefix;
    }
    if (pass == 3) wsf[OFF_THR + b] = funmap(prefix);
}

// ---------------- K3: one-shot fused aggregation + OHEM text-dice ----------------
__global__ __launch_bounds__(NTHR, 2) void k_pix(const float* __restrict__ preds,
                      const int* __restrict__ text,
                      const int* __restrict__ mask,
                      unsigned* __restrict__ wsu) {
    float* wsf = (float*)wsu;
    const int b = blockIdx.y;
    const int tid = threadIdx.x;
    const int lane = tid & 63;
    __shared__ float stbl[45];
    __shared__ float sred[4];
    __shared__ float sthr;
    __shared__ unsigned sfb;
    if (tid < 45) stbl[tid] = wsf[OFF_TBL + b * 45 + tid];
    if (tid < 4) sred[tid] = 0.f;
    if (tid == 0) { sthr = wsf[OFF_THR + b]; sfb = wsu[OFF_FB + b]; }
    __syncthreads();
    const float thr = sthr;
    const bool fb = sfb != 0u;
    float r_at = 0.f, r_bt = 0.f, r_ct = 0.f, r_ag = 0.f;
    const int base = blockIdx.x * (NTHR * 4) + tid * 4;
    const int* tb = text + b * HW;
    const int* mb = mask + b * HW;
    const float* p0 = preds + (size_t)(b * 6) * HW;
    const float* e0 = preds + (size_t)(b * 6 + 2) * HW;
    const float* e1 = e0 + HW;
    const float* e2 = e0 + 2 * HW;
    const float* e3 = e0 + 3 * HW;
    const int4 t4 = *(const int4*)(tb + base);
    const int4 m4 = *(const int4*)(mb + base);
    const float4 s4 = *(const float4*)(p0 + base);
    const float4 a4 = *(const float4*)(e0 + base);
    const float4 b4 = *(const float4*)(e1 + base);
    const float4 c4 = *(const float4*)(e2 + base);
    const float4 d4 = *(const float4*)(e3 + base);

#define PPIX(T, M, S, A, B, C, D) do {                                       \
        bool pos_ = (T) > 0;                                                 \
        bool samp_ = fb ? ((M) > 0) : ((((S) >= thr) || pos_) && ((M) > 0)); \
        float sg_ = 1.f / (1.f + expf(-(S)));                                \
        float smf_ = samp_ ? 1.f : 0.f;                                      \
        float it_ = pos_ ? 1.f : 0.f;                                        \
        r_at += smf_ * sg_ * it_;                                            \
        r_bt += smf_ * sg_ * sg_;                                            \
        r_ct += smf_ * it_;                                                  \
        int t5_ = min((T), 8) * 5;                                           \
        float d0_ = (A) - stbl[t5_ + 0];                                     \
        float d1_ = (B) - stbl[t5_ + 1];                                     \
        float d2_ = (C) - stbl[t5_ + 2];                                     \
        float d3_ = (D) - stbl[t5_ + 3];                                     \
        float w_ = stbl[t5_ + 4];                                            \
        float sq_ = d0_ * d0_ + d1_ * d1_ + d2_ * d2_ + d3_ * d3_;           \
        float dist_ = sqrtf(sq_ + 1e-12f) - 0.5f;                            \
        float hp_ = fmaxf(dist_, 0.f);                                       \
        r_ag += w_ * log1pf(hp_ * hp_);                                      \
    } while (0)

    PPIX(t4.x, m4.x, s4.x, a4.x, b4.x, c4.x, d4.x);
    PPIX(t4.y, m4.y, s4.y, a4.y, b4.y, c4.y, d4.y);
    PPIX(t4.z, m4.z, s4.z, a4.z, b4.z, c4.z, d4.z);
    PPIX(t4.w, m4.w, s4.w, a4.w, b4.w, c4.w, d4.w);
#undef PPIX

    {
        float v = wred(r_at); if (lane == 0) atomicAdd(&sred[0], v);
        v = wred(r_bt); if (lane == 0) atomicAdd(&sred[1], v);
        v = wred(r_ct); if (lane == 0) atomicAdd(&sred[2], v);
        v = wred(r_ag); if (lane == 0) atomicAdd(&sred[3], v);
    }
    __syncthreads();
    if (tid < 4) {
        const int rep = blockIdx.x & (REP - 1);
        atomicAdd(&wsf[OFF_PACC + rep * PACC_STRIDE + b * 4 + tid], sred[tid]);
    }
}

// ---------------- K4: final assembly ----------------
__global__ void k_final(unsigned* __restrict__ wsu, float* __restrict__ out) {
    float* wsf = (float*)wsu;
    __shared__ float lt[NB], lk[NB], la[NB], ld[NB];
    int b = threadIdx.x;
    if (b < NB) {
        const float S = 1e-3f;
        float ak = 0.f, bk = 0.f, ck = 0.f, at = 0.f, bt = 0.f, ct = 0.f, ag = 0.f;
#pragma unroll
        for (int r = 0; r < REP; r++) {
            ak += wsf[OFF_ACC + r * ACC_STRIDE + b * 52 + 49];
            bk += wsf[OFF_ACC + r * ACC_STRIDE + b * 52 + 50];
            ck += wsf[OFF_ACC + r * ACC_STRIDE + b * 52 + 51];
            at += wsf[OFF_PACC + r * PACC_STRIDE + b * 4 + 0];
            bt += wsf[OFF_PACC + r * PACC_STRIDE + b * 4 + 1];
            ct += wsf[OFF_PACC + r * PACC_STRIDE + b * 4 + 2];
            ag += wsf[OFF_PACC + r * PACC_STRIDE + b * 4 + 3];
        }
        lt[b] = 1.f - 2.f * (at + S) / ((bt + S) + (ct + S));
        lk[b] = 1.f - 2.f * (ak + S) / ((bk + S) + (ck + S));
        int nval = (int)wsu[OFF_NVAL + b];
        la[b] = (nval > 0) ? ag / fmaxf((float)nval, 1.f) : 0.f;
        ld[b] = wsf[OFF_DISCR + b];
    }
    __syncthreads();
    if (b == 0) {
        float st = 0, sk = 0, sa = 0, sd = 0;
        for (int i = 0; i < NB; i++) { st += lt[i]; sk += lk[i]; sa += la[i]; sd += ld[i]; }
        out[0] = st / NB;
        out[1] = 0.5f * sk / NB;
        out[2] = 0.25f * sa / NB;
        out[3] = 0.25f * sd / NB;
    }
}

extern "C" void kernel_launch(void* const* d_in, const int* in_sizes, int n_in,
                              void* d_out, int out_size, void* d_ws, size_t ws_size,
                              hipStream_t stream) {
    const float* preds = (const float*)d_in[0];
    const int* text = (const int*)d_in[1];
    const int* kern = (const int*)d_in[2];
    const int* mask = (const int*)d_in[3];
    unsigned* wsu = (unsigned*)d_ws;
    float* out = (float*)d_out;

    const int do_compact = (ws_size >= WS_FULL_BYTES) ? 1 : 0;

    hipMemsetAsync(d_ws, 0, (size_t)ZERO_WORDS * 4, stream);

    dim3 grid(GX, NB);
    k_stats<<<grid, NTHR, 0, stream>>>(preds, text, kern, mask, wsu, do_compact);
    k_sel<<<NB, 1024, 0, stream>>>(wsu, do_compact);
    if (!do_compact) {
        dim3 hgrid(128, NB);
        for (int pass = 0; pass < 4; pass++) {
            k_hist<<<hgrid, NTHR, 0, stream>>>(preds, text, wsu, pass);
            k_select<<<1, 64, 0, stream>>>(wsu, pass);
        }
    }
    k_pix<<<grid, NTHR, 0, stream>>>(preds, text, mask, wsu);
    k_final<<<1, 64, 0, stream>>>(wsu, out);
}

// Round 6
// 243.737 us; speedup vs baseline: 2.2056x; 1.0681x over previous
//
#include <hip/hip_runtime.h>
#include <math.h>

#define HW (512 * 512)
#define NB 16
#define NTHR 256
#define GXS 64          // blocks per batch: 64 blocks * 256 thr * 16 px = HW
#define CH 4            // chunks per thread (4 px each)
#define NSEG 256        // waves per batch = segments
#define SEGSZ 1024      // max keys per segment
#define REP 16          // accumulator replicas to spread hot atomic lines

// ---- workspace layout (4-byte words) ----
// zeroed region:
#define OFF_ACC    0                           // f [REP][NB*52]  k_stats accum
#define ACC_STRIDE (NB * 52)                   // 832
#define OFF_PACC   (OFF_ACC + REP * ACC_STRIDE)    // f [REP][NB*4] k_pix accum
#define PACC_STRIDE (NB * 4)                   // 64
#define OFF_HISTFB (OFF_PACC + REP * PACC_STRIDE)  // u [4][16][256] fallback hists
#define OFF_NEGMX  (OFF_HISTFB + 4 * 16 * 256) // u [NB][REP]: max(~key) over negs
#define ZERO_WORDS (OFF_NEGMX + NB * REP)
// non-zeroed region (written unconditionally before read):
#define OFF_TBL    ZERO_WORDS                  // f [16][9][5] rows0..8={a0..a3,w}
#define OFF_THR    (OFF_TBL + 16 * 45)         // f [16]
#define OFF_FB     (OFF_THR + 16)              // u [16]
#define OFF_NVAL   (OFF_FB + 16)               // u [16]
#define OFF_DISCR  (OFF_NVAL + 16)             // f [16]
#define OFF_PREFIX (OFF_DISCR + 16)            // u [16] fallback select state
#define OFF_KKC    (OFF_PREFIX + 16)           // u [16]
#define OFF_NEGC   (OFF_KKC + 16)              // u [16]
#define OFF_CNTS   (OFF_NEGC + 16)             // u [NB][NSEG] per-wave seg counts
#define OFF_KEYS   (OFF_CNTS + NB * NSEG)      // u [NB][NSEG][SEGSZ] compacted keys
#define WS_FULL_BYTES ((size_t)(OFF_KEYS + NB * HW) * 4)

// acc value indices: 0-7 kcnt, 8-15 tcnt, 16-47 ksum, 48 pos, 49 ak, 50 bk, 51 ck

__device__ __forceinline__ unsigned fmap(float f) {
    unsigned u = __float_as_uint(f);
    return (u & 0x80000000u) ? ~u : (u | 0x80000000u);
}
__device__ __forceinline__ float funmap(unsigned u) {
    return (u & 0x80000000u) ? __uint_as_float(u & 0x7FFFFFFFu)
                             : __uint_as_float(~u);
}
__device__ __forceinline__ float wred(float x) {
#pragma unroll
    for (int o = 32; o; o >>= 1) x += __shfl_xor(x, o);
    return x;
}
__device__ __forceinline__ unsigned wredu(unsigned x) {
#pragma unroll
    for (int o = 32; o; o >>= 1) x += __shfl_xor(x, o);
    return x;
}
__device__ __forceinline__ unsigned wredumax(unsigned x) {
#pragma unroll
    for (int o = 32; o; o >>= 1) x = max(x, (unsigned)__shfl_xor((int)x, o));
    return x;
}

// ---------------- K1: stats + kernel-dice + segment compaction ----------------
// Atomic-free hot loop (round-3 lesson); 16 px/thread to amortize the fixed
// 35-value butterfly + atomic epilogue (round-5 lesson: one-shot 4px/thread made
// the epilogue's 210 ds_swizzle chain the dominant stall). unroll 1 keeps live
// regs bounded (round-2 lesson: spills at default occupancy target).
__global__ __launch_bounds__(NTHR, 2) void k_stats(const float* __restrict__ preds,
                        const int* __restrict__ text,
                        const int* __restrict__ kern,
                        const int* __restrict__ mask,
                        unsigned* __restrict__ wsu, int do_compact) {
    float* wsf = (float*)wsu;
    const int b = blockIdx.y;
    const int tid = threadIdx.x;
    const int lane = tid & 63;
    const unsigned long long lmask = (1ull << lane) - 1ull;
    __shared__ float sacc[52];
    if (tid < 52) sacc[tid] = 0.f;
    __syncthreads();

    const int* tb = text + b * HW;
    const int* kb = kern + b * HW;
    const int* mb = mask + b * HW;
    const float* p0 = preds + (size_t)(b * 6 + 0) * HW;
    const float* p1 = preds + (size_t)(b * 6 + 1) * HW;
    const float* e0 = preds + (size_t)(b * 6 + 2) * HW;
    const float* e1 = e0 + HW;
    const float* e2 = e0 + 2 * HW;
    const float* e3 = e0 + 3 * HW;

    const int seg = blockIdx.x * 4 + (tid >> 6);
    unsigned* keys = wsu + OFF_KEYS + (size_t)b * HW + (size_t)seg * SEGSZ;
    unsigned segoff = 0;
    unsigned mkAll = 0u;

    float ks[32];
#pragma unroll
    for (int i = 0; i < 32; i++) ks[i] = 0.f;
    float r_ak = 0.f, r_bk = 0.f, r_ck = 0.f;
    unsigned kcW[8] = {0, 0, 0, 0, 0, 0, 0, 0};
    unsigned tcW[8] = {0, 0, 0, 0, 0, 0, 0, 0};
    unsigned posW = 0;

#pragma unroll 1
    for (int c = 0; c < CH; c++) {
        const int base = blockIdx.x * (NTHR * 4 * CH) + c * (NTHR * 4) + tid * 4;
        const int4 t4 = *(const int4*)(tb + base);
        const int4 k4 = *(const int4*)(kb + base);
        const int4 m4 = *(const int4*)(mb + base);
        const float4 s4 = *(const float4*)(p0 + base);
        const float4 q4 = *(const float4*)(p1 + base);
        const float4 a4 = *(const float4*)(e0 + base);
        const float4 b4 = *(const float4*)(e1 + base);
        const float4 c4 = *(const float4*)(e2 + base);
        const float4 d4 = *(const float4*)(e3 + base);

#define PIX(T, K, M, Q, A, B, C, D) do {                                     \
        bool pos_ = (T) > 0, mp_ = (M) > 0;                                  \
        float sm_ = (pos_ && mp_) ? 1.f : 0.f;                               \
        float sg_ = 1.f / (1.f + expf(-(Q)));                                \
        float ik_ = ((K) > 0) ? 1.f : 0.f;                                   \
        r_ak += sm_ * sg_ * ik_;                                             \
        r_bk += sm_ * sg_ * sg_;                                             \
        r_ck += sm_ * ik_;                                                   \
        posW += (unsigned)__popcll(__ballot(pos_ && mp_));                   \
        _Pragma("unroll")                                                    \
        for (int i_ = 0; i_ < 8; i_++) {                                     \
            bool hit_ = ((K) == i_ + 1);                                     \
            kcW[i_] += (unsigned)__popcll(__ballot(hit_));                   \
            tcW[i_] += (unsigned)__popcll(__ballot((T) == i_ + 1));          \
            float h_ = hit_ ? 1.f : 0.f;                                     \
            ks[i_ * 4 + 0] += h_ * (A);                                      \
            ks[i_ * 4 + 1] += h_ * (B);                                      \
            ks[i_ * 4 + 2] += h_ * (C);                                      \
            ks[i_ * 4 + 3] += h_ * (D);                                      \
        }                                                                    \
    } while (0)

        PIX(t4.x, k4.x, m4.x, q4.x, a4.x, b4.x, c4.x, d4.x);
        PIX(t4.y, k4.y, m4.y, q4.y, a4.y, b4.y, c4.y, d4.y);
        PIX(t4.z, k4.z, m4.z, q4.z, a4.z, b4.z, c4.z, d4.z);
        PIX(t4.w, k4.w, m4.w, q4.w, a4.w, b4.w, c4.w, d4.w);
#undef PIX

        // ---- deterministic segment compaction (no atomics) ----
        const unsigned long long m0 = __ballot(t4.x == 0);
        const unsigned long long m1 = __ballot(t4.y == 0);
        const unsigned long long m2 = __ballot(t4.z == 0);
        const unsigned long long m3 = __ballot(t4.w == 0);
        const unsigned c0 = (unsigned)__popcll(m0), c1 = (unsigned)__popcll(m1);
        const unsigned c2 = (unsigned)__popcll(m2), c3 = (unsigned)__popcll(m3);
        if (do_compact) {
            if (t4.x == 0) keys[segoff + (unsigned)__popcll(m0 & lmask)] = fmap(s4.x);
            if (t4.y == 0) keys[segoff + c0 + (unsigned)__popcll(m1 & lmask)] = fmap(s4.y);
            if (t4.z == 0) keys[segoff + c0 + c1 + (unsigned)__popcll(m2 & lmask)] = fmap(s4.z);
            if (t4.w == 0) keys[segoff + c0 + c1 + c2 + (unsigned)__popcll(m3 & lmask)] = fmap(s4.w);
        }
        segoff += c0 + c1 + c2 + c3;
        // ---- min negative score via max(~key) ----
        unsigned mk = 0u;
        if (t4.x == 0) mk = max(mk, ~fmap(s4.x));
        if (t4.y == 0) mk = max(mk, ~fmap(s4.y));
        if (t4.z == 0) mk = max(mk, ~fmap(s4.z));
        if (t4.w == 0) mk = max(mk, ~fmap(s4.w));
        mkAll = max(mkAll, mk);
    }

    if (lane == 0) wsu[OFF_CNTS + b * NSEG + seg] = segoff;
    mkAll = wredumax(mkAll);
    if (lane == 0 && mkAll)
        atomicMax(&wsu[OFF_NEGMX + b * REP + (blockIdx.x & (REP - 1))], mkAll);

    // ---- epilogue: wave butterfly -> LDS -> one replica atomic per value ----
#pragma unroll
    for (int i = 0; i < 32; i++) {
        float v = wred(ks[i]);
        if (lane == 0) atomicAdd(&sacc[16 + i], v);
    }
    {
        float v = wred(r_ak); if (lane == 0) atomicAdd(&sacc[49], v);
        v = wred(r_bk); if (lane == 0) atomicAdd(&sacc[50], v);
        v = wred(r_ck); if (lane == 0) atomicAdd(&sacc[51], v);
    }
    if (lane == 0) {
#pragma unroll
        for (int i = 0; i < 8; i++) {
            atomicAdd(&sacc[i], (float)kcW[i]);
            atomicAdd(&sacc[8 + i], (float)tcW[i]);
        }
        atomicAdd(&sacc[48], (float)posW);
    }
    __syncthreads();
    if (tid < 52) {
        const int rep = blockIdx.x & (REP - 1);
        atomicAdd(&wsf[OFF_ACC + rep * ACC_STRIDE + b * 52 + tid], sacc[tid]);
    }
}

// ---------------- K2: setup + OHEM threshold ----------------
// Fast path: neg_num == neg => threshold = min negative score (pure reduction).
// Radix select over compacted segments only when 3*pos < neg.
__global__ void k_sel(unsigned* __restrict__ wsu, int do_select) {
    float* wsf = (float*)wsu;
    const int b = blockIdx.x;
    const int tid = threadIdx.x;   // 256 threads; tid == segment id
    const int lane = tid & 63;
    __shared__ float s_acc[52];
    __shared__ float s_avg[8][4];
    __shared__ int s_valid[8];
    __shared__ unsigned s_hist[256];
    __shared__ unsigned s_negtot;
    __shared__ unsigned s_kk, s_prefix;

    if (tid < 52) {
        float v = 0.f;
#pragma unroll
        for (int r = 0; r < REP; r++) v += wsf[OFF_ACC + r * ACC_STRIDE + b * 52 + tid];
        s_acc[tid] = v;
    }
    if (tid == 0) s_negtot = 0u;
    __syncthreads();

    const unsigned myc = wsu[OFF_CNTS + b * NSEG + tid];
    {
        unsigned cw = wredu(myc);
        if (lane == 0) atomicAdd(&s_negtot, cw);
    }
    if (tid < 8) {
        float kcf = s_acc[tid];
        float tcf = s_acc[8 + tid];
        int valid = (kcf > 0.f && tcf > 0.f) ? 1 : 0;
        float inv = 1.f / fmaxf(kcf, 1.f);
        float w = valid ? 1.f / fmaxf(tcf, 1.f) : 0.f;
#pragma unroll
        for (int c = 0; c < 4; c++) {
            float a = s_acc[16 + tid * 4 + c] * inv;
            s_avg[tid][c] = a;
            wsf[OFF_TBL + b * 45 + (tid + 1) * 5 + c] = a;
        }
        s_valid[tid] = valid;
        wsf[OFF_TBL + b * 45 + (tid + 1) * 5 + 4] = w;
    }
    if (tid >= 8 && tid < 13) wsf[OFF_TBL + b * 45 + (tid - 8)] = 0.f;  // bg row
    __syncthreads();
    if (tid == 0) {
        int nval = 0;
        for (int i = 0; i < 8; i++) nval += s_valid[i];
        float L = 0.f;
        for (int i = 0; i < 8; i++)
            for (int j = i + 1; j < 8; j++)
                if (s_valid[i] && s_valid[j]) {
                    float sq = 0.f;
                    for (int c = 0; c < 4; c++) {
                        float d = s_avg[i][c] - s_avg[j][c];
                        sq += d * d;
                    }
                    float h = fmaxf(3.0f - sqrtf(sq), 0.f);
                    L += log1pf(h * h);
                }
        wsf[OFF_DISCR + b] = (nval > 1) ? L / fmaxf((float)(nval * (nval - 1)), 1.f) : 0.f;
        wsu[OFF_NVAL + b] = (unsigned)nval;
        unsigned pos = (unsigned)s_acc[48];
        unsigned neg = s_negtot;
        wsu[OFF_NEGC + b] = neg;
        unsigned nn = min(pos * 3u, neg);
        int fb = (pos == 0u || nn == 0u) ? 1 : 0;
        wsu[OFF_FB + b] = (unsigned)fb;
        wsu[OFF_KKC + b] = fb ? 0u : nn;   // fallback path state
        wsu[OFF_PREFIX + b] = 0u;
        wsf[OFF_THR + b] = 0.f;
        unsigned kk = fb ? 0u : nn;
        if (!fb && nn == neg) {
            // fast path: threshold = min negative score
            unsigned mx = 0u;
#pragma unroll
            for (int r = 0; r < REP; r++) mx = max(mx, wsu[OFF_NEGMX + b * REP + r]);
            wsf[OFF_THR + b] = funmap(~mx);
            kk = 0u;                        // skip radix
        }
        s_kk = kk;
        s_prefix = 0u;
    }
    __syncthreads();
    if (!do_select) return;
    if (s_kk == 0u) return;                 // uniform: fb or fast path
    const unsigned* keys = wsu + OFF_KEYS + (size_t)b * HW + (size_t)tid * SEGSZ;
    unsigned prefix = 0u;
    for (int pass = 0; pass < 4; pass++) {
        const int shift = 24 - 8 * pass;
        const unsigned fmask = (pass == 0) ? 0u : (0xFFFFFFFFu << (shift + 8));
        s_hist[tid] = 0u;
        __syncthreads();
        for (unsigned i = 0; i < myc; i++) {
            unsigned key = keys[i];
            if ((key & fmask) == prefix) atomicAdd(&s_hist[(key >> shift) & 255u], 1u);
        }
        __syncthreads();
        if (tid == 0) {
            unsigned k2 = s_kk;
            for (int bin = 255; bin >= 0; --bin) {
                unsigned c = s_hist[bin];
                if (k2 <= c) { s_prefix = prefix | (((unsigned)bin) << shift); s_kk = k2; break; }
                k2 -= c;
            }
        }
        __syncthreads();
        prefix = s_prefix;
    }
    if (tid == 0) wsf[OFF_THR + b] = funmap(prefix);
}

// ---------------- fallback radix select over raw data (only if ws too small) ----------------
__global__ void k_hist(const float* __restrict__ preds, const int* __restrict__ text,
                       unsigned* __restrict__ wsu, int pass) {
    const int b = blockIdx.y;
    const int tid = threadIdx.x;
    __shared__ unsigned h[256];
    h[tid] = 0u;
    __syncthreads();
    const unsigned prefix = wsu[OFF_PREFIX + b];
    const int shift = 24 - 8 * pass;
    const unsigned fmask = (pass == 0) ? 0u : (0xFFFFFFFFu << (shift + 8));
    const int* tb = text + b * HW;
    const float* pt = preds + (size_t)(b * 6) * HW;
    for (int p = blockIdx.x * NTHR + tid; p < HW; p += gridDim.x * NTHR) {
        if (tb[p] == 0) {
            unsigned key = fmap(pt[p]);
            if ((key & fmask) == prefix) atomicAdd(&h[(key >> shift) & 255u], 1u);
        }
    }
    __syncthreads();
    if (h[tid]) atomicAdd(&wsu[OFF_HISTFB + pass * 4096 + b * 256 + tid], h[tid]);
}
__global__ void k_select(unsigned* __restrict__ wsu, int pass) {
    int b = threadIdx.x;
    if (b >= NB) return;
    float* wsf = (float*)wsu;
    unsigned k = wsu[OFF_KKC + b];
    unsigned prefix = wsu[OFF_PREFIX + b];
    const int shift = 24 - 8 * pass;
    const unsigned* h = &wsu[OFF_HISTFB + pass * 4096 + b * 256];
    if (k > 0) {
        for (int bin = 255; bin >= 0; --bin) {
            unsigned c = h[bin];
            if (k <= c) { prefix |= ((unsigned)bin) << shift; break; }
            k -= c;
        }
        wsu[OFF_KKC + b] = k;
        wsu[OFF_PREFIX + b] = prefix;
    }
    if (pass == 3) wsf[OFF_THR + b] = funmap(prefix);
}

// ---------------- K3: fused aggregation + OHEM text-dice (16 px/thread) ----------------
__global__ __launch_bounds__(NTHR, 2) void k_pix(const float* __restrict__ preds,
                      const int* __restrict__ text,
                      const int* __restrict__ mask,
                      unsigned* __restrict__ wsu) {
    float* wsf = (float*)wsu;
    const int b = blockIdx.y;
    const int tid = threadIdx.x;
    const int lane = tid & 63;
    __shared__ float stbl[45];
    __shared__ float sred[4];
    __shared__ float sthr;
    __shared__ unsigned sfb;
    if (tid < 45) stbl[tid] = wsf[OFF_TBL + b * 45 + tid];
    if (tid < 4) sred[tid] = 0.f;
    if (tid == 0) { sthr = wsf[OFF_THR + b]; sfb = wsu[OFF_FB + b]; }
    __syncthreads();
    const float thr = sthr;
    const bool fb = sfb != 0u;
    float r_at = 0.f, r_bt = 0.f, r_ct = 0.f, r_ag = 0.f;
    const int* tb = text + b * HW;
    const int* mb = mask + b * HW;
    const float* p0 = preds + (size_t)(b * 6) * HW;
    const float* e0 = preds + (size_t)(b * 6 + 2) * HW;
    const float* e1 = e0 + HW;
    const float* e2 = e0 + 2 * HW;
    const float* e3 = e0 + 3 * HW;

#pragma unroll 1
    for (int c = 0; c < CH; c++) {
        const int base = blockIdx.x * (NTHR * 4 * CH) + c * (NTHR * 4) + tid * 4;
        const int4 t4 = *(const int4*)(tb + base);
        const int4 m4 = *(const int4*)(mb + base);
        const float4 s4 = *(const float4*)(p0 + base);
        const float4 a4 = *(const float4*)(e0 + base);
        const float4 b4 = *(const float4*)(e1 + base);
        const float4 c4 = *(const float4*)(e2 + base);
        const float4 d4 = *(const float4*)(e3 + base);

#define PPIX(T, M, S, A, B, C, D) do {                                       \
        bool pos_ = (T) > 0;                                                 \
        bool samp_ = fb ? ((M) > 0) : ((((S) >= thr) || pos_) && ((M) > 0)); \
        float sg_ = 1.f / (1.f + expf(-(S)));                                \
        float smf_ = samp_ ? 1.f : 0.f;                                      \
        float it_ = pos_ ? 1.f : 0.f;                                        \
        r_at += smf_ * sg_ * it_;                                            \
        r_bt += smf_ * sg_ * sg_;                                            \
        r_ct += smf_ * it_;                                                  \
        int t5_ = min((T), 8) * 5;                                           \
        float d0_ = (A) - stbl[t5_ + 0];                                     \
        float d1_ = (B) - stbl[t5_ + 1];                                     \
        float d2_ = (C) - stbl[t5_ + 2];                                     \
        float d3_ = (D) - stbl[t5_ + 3];                                     \
        float w_ = stbl[t5_ + 4];                                            \
        float sq_ = d0_ * d0_ + d1_ * d1_ + d2_ * d2_ + d3_ * d3_;           \
        float dist_ = sqrtf(sq_ + 1e-12f) - 0.5f;                            \
        float hp_ = fmaxf(dist_, 0.f);                                       \
        r_ag += w_ * log1pf(hp_ * hp_);                                      \
    } while (0)

        PPIX(t4.x, m4.x, s4.x, a4.x, b4.x, c4.x, d4.x);
        PPIX(t4.y, m4.y, s4.y, a4.y, b4.y, c4.y, d4.y);
        PPIX(t4.z, m4.z, s4.z, a4.z, b4.z, c4.z, d4.z);
        PPIX(t4.w, m4.w, s4.w, a4.w, b4.w, c4.w, d4.w);
#undef PPIX
    }

    {
        float v = wred(r_at); if (lane == 0) atomicAdd(&sred[0], v);
        v = wred(r_bt); if (lane == 0) atomicAdd(&sred[1], v);
        v = wred(r_ct); if (lane == 0) atomicAdd(&sred[2], v);
        v = wred(r_ag); if (lane == 0) atomicAdd(&sred[3], v);
    }
    __syncthreads();
    if (tid < 4) {
        const int rep = blockIdx.x & (REP - 1);
        atomicAdd(&wsf[OFF_PACC + rep * PACC_STRIDE + b * 4 + tid], sred[tid]);
    }
}

// ---------------- K4: final assembly ----------------
__global__ void k_final(unsigned* __restrict__ wsu, float* __restrict__ out) {
    float* wsf = (float*)wsu;
    __shared__ float lt[NB], lk[NB], la[NB], ld[NB];
    int b = threadIdx.x;
    if (b < NB) {
        const float S = 1e-3f;
        float ak = 0.f, bk = 0.f, ck = 0.f, at = 0.f, bt = 0.f, ct = 0.f, ag = 0.f;
#pragma unroll
        for (int r = 0; r < REP; r++) {
            ak += wsf[OFF_ACC + r * ACC_STRIDE + b * 52 + 49];
            bk += wsf[OFF_ACC + r * ACC_STRIDE + b * 52 + 50];
            ck += wsf[OFF_ACC + r * ACC_STRIDE + b * 52 + 51];
            at += wsf[OFF_PACC + r * PACC_STRIDE + b * 4 + 0];
            bt += wsf[OFF_PACC + r * PACC_STRIDE + b * 4 + 1];
            ct += wsf[OFF_PACC + r * PACC_STRIDE + b * 4 + 2];
            ag += wsf[OFF_PACC + r * PACC_STRIDE + b * 4 + 3];
        }
        lt[b] = 1.f - 2.f * (at + S) / ((bt + S) + (ct + S));
        lk[b] = 1.f - 2.f * (ak + S) / ((bk + S) + (ck + S));
        int nval = (int)wsu[OFF_NVAL + b];
        la[b] = (nval > 0) ? ag / fmaxf((float)nval, 1.f) : 0.f;
        ld[b] = wsf[OFF_DISCR + b];
    }
    __syncthreads();
    if (b == 0) {
        float st = 0, sk = 0, sa = 0, sd = 0;
        for (int i = 0; i < NB; i++) { st += lt[i]; sk += lk[i]; sa += la[i]; sd += ld[i]; }
        out[0] = st / NB;
        out[1] = 0.5f * sk / NB;
        out[2] = 0.25f * sa / NB;
        out[3] = 0.25f * sd / NB;
    }
}

extern "C" void kernel_launch(void* const* d_in, const int* in_sizes, int n_in,
                              void* d_out, int out_size, void* d_ws, size_t ws_size,
                              hipStream_t stream) {
    const float* preds = (const float*)d_in[0];
    const int* text = (const int*)d_in[1];
    const int* kern = (const int*)d_in[2];
    const int* mask = (const int*)d_in[3];
    unsigned* wsu = (unsigned*)d_ws;
    float* out = (float*)d_out;

    const int do_compact = (ws_size >= WS_FULL_BYTES) ? 1 : 0;

    hipMemsetAsync(d_ws, 0, (size_t)ZERO_WORDS * 4, stream);

    dim3 grid(GXS, NB);
    k_stats<<<grid, NTHR, 0, stream>>>(preds, text, kern, mask, wsu, do_compact);
    k_sel<<<NB, NTHR, 0, stream>>>(wsu, do_compact);
    if (!do_compact) {
        dim3 hgrid(128, NB);
        for (int pass = 0; pass < 4; pass++) {
            k_hist<<<hgrid, NTHR, 0, stream>>>(preds, text, wsu, pass);
            k_select<<<1, 64, 0, stream>>>(wsu, pass);
        }
    }
    k_pix<<<grid, NTHR, 0, stream>>>(preds, text, mask, wsu);
    k_final<<<1, 64, 0, stream>>>(wsu, out);
}